// Round 4
// baseline (267.730 us; speedup 1.0000x reference)
//
#include <hip/hip_runtime.h>
#include <stddef.h>

constexpr int FEAT = 256;
constexpr int F4   = FEAT / 4;       // 64 float4 per row
constexpr int NCLS = 345;
constexpr int NDOM = 6;
constexpr int NSEG = NCLS * NDOM;    // 2070
constexpr int SB   = 256;            // scatter blocks (== k_bases block size)
constexpr int MAXT = 512;            // max rows per partial tile (LDS sizing)
constexpr float BETA = 0.5f;
constexpr float EPS  = 1e-5f;

typedef float f32x4 __attribute__((ext_vector_type(4)));

// ---- zero the global accumulator ----
__global__ void k_zero_accum(float* __restrict__ accum) {
    int i = blockIdx.x * blockDim.x + threadIdx.x;     // one f32x4 each
    if (i < NSEG * F4) reinterpret_cast<f32x4*>(accum)[i] = (f32x4)0.0f;
}

// ---- phase A: seg[] + per-block histogram (no global atomics) ----
__global__ void __launch_bounds__(256)
k_seg_hist(const int* __restrict__ labels, const int* __restrict__ domains,
           int n, int chunk, int* __restrict__ seg, int* __restrict__ W) {
    __shared__ int h[NSEG];
    for (int i = threadIdx.x; i < NSEG; i += blockDim.x) h[i] = 0;
    __syncthreads();
    const int b  = blockIdx.x;
    const int lo = b * chunk;
    const int hi = min(n, lo + chunk);
    for (int i = lo + threadIdx.x; i < hi; i += blockDim.x) {
        int s = domains[i] * NCLS + labels[i];
        seg[i] = s;
        atomicAdd(&h[s], 1);
    }
    __syncthreads();
    int* Wb = W + (size_t)b * NSEG;
    for (int i = threadIdx.x; i < NSEG; i += blockDim.x) Wb[i] = h[i];
}

// ---- phase B1: totals[seg] = sum_b W[b][seg] ----
__global__ void k_totals(const int* __restrict__ W, int* __restrict__ totals) {
    const int s = blockIdx.x;
    const int t = threadIdx.x;  // 64 threads
    int sum = 0;
    for (int b = t; b < SB; b += 64) sum += W[(size_t)b * NSEG + s];
    for (int off = 1; off < 64; off <<= 1) sum += __shfl_xor(sum, off, 64);
    if (t == 0) totals[s] = sum;
}

// ---- phase B2: exclusive scan of totals -> offsets (single block) ----
__global__ void k_scan(const int* __restrict__ totals, int* __restrict__ offsets) {
    constexpr int T  = 256;
    constexpr int CH = (NSEG + T - 1) / T;  // 9
    __shared__ int csum[T];
    int t = threadIdx.x;
    int base = t * CH;
    int sum = 0;
    for (int j = 0; j < CH; ++j) {
        int idx = base + j;
        if (idx < NSEG) sum += totals[idx];
    }
    csum[t] = sum;
    __syncthreads();
    for (int off = 1; off < T; off <<= 1) {
        int v = (t >= off) ? csum[t - off] : 0;
        __syncthreads();
        csum[t] += v;
        __syncthreads();
    }
    int run = csum[t] - sum;
    for (int j = 0; j < CH; ++j) {
        int idx = base + j;
        if (idx < NSEG) {
            offsets[idx] = run;
            run += totals[idx];
        }
    }
}

// ---- phase B3: per-block bases Bmat[b][seg] ----
__global__ void __launch_bounds__(256)
k_bases(const int* __restrict__ W, const int* __restrict__ offsets,
        int* __restrict__ Bmat) {
    const int s = blockIdx.x;
    const int t = threadIdx.x;  // 256 == SB
    __shared__ int sc[SB];
    int w = W[(size_t)t * NSEG + s];
    sc[t] = w;
    __syncthreads();
    for (int off = 1; off < SB; off <<= 1) {
        int v = (t >= off) ? sc[t - off] : 0;
        __syncthreads();
        sc[t] += v;
        __syncthreads();
    }
    Bmat[(size_t)t * NSEG + s] = offsets[s] + (sc[t] - w);
}

// ---- phase C: scatter row indices + their segment ids (LDS cursors only) ----
__global__ void __launch_bounds__(256)
k_scatter(const int* __restrict__ seg, int n, int chunk,
          const int* __restrict__ Bmat, int* __restrict__ sorted,
          int* __restrict__ sseg) {
    __shared__ int cur[NSEG];
    const int b = blockIdx.x;
    const int* Bb = Bmat + (size_t)b * NSEG;
    for (int i = threadIdx.x; i < NSEG; i += blockDim.x) cur[i] = Bb[i];
    __syncthreads();
    const int lo = b * chunk;
    const int hi = min(n, lo + chunk);
    for (int i = lo + threadIdx.x; i < hi; i += blockDim.x) {
        int s = seg[i];
        int pos = atomicAdd(&cur[s], 1);
        sorted[pos] = i;
        sseg[pos]   = s;
    }
}

// ---- phase D: uniform tiles of sorted positions -> run-wise register sums ----
__global__ void __launch_bounds__(256)
k_partial(const float* __restrict__ feats, const int* __restrict__ sorted,
          const int* __restrict__ sseg, int n, int tpt,
          float* __restrict__ accum) {
    __shared__ int idx[MAXT];
    __shared__ int ssg[MAXT];
    const int t  = blockIdx.x;
    const int lo = t * tpt;
    const int hi = min(n, lo + tpt);
    const int len = hi - lo;
    if (len <= 0) return;
    for (int i = threadIdx.x; i < len; i += 256) {
        idx[i] = sorted[lo + i];
        ssg[i] = sseg[lo + i];
    }
    __syncthreads();

    const int lane = threadIdx.x & 63;   // f4 column
    const int rp   = threadIdx.x >> 6;   // wave id 0..3
    const int per  = (len + 3) >> 2;
    const int r0 = rp * per;
    const int r1 = min(len, r0 + per);

    int r = r0;
    while (r < r1) {
        const int cs = ssg[r];
        // find run end e in [r, r1) -- 64 entries per ballot step
        int e = r;
        for (;;) {
            int p = e + lane;
            int v = (p < r1) ? ssg[p] : (cs + 1);
            unsigned long long m = __ballot(v != cs);
            if (m) { e += (int)(__ffsll((long long)m) - 1); break; }
            e += 64;
        }
        // accumulate run [r, e): 8 rows in flight
        f32x4 acc = (f32x4)0.0f;
        int rr = r;
        for (; rr + 7 < e; rr += 8) {
            f32x4 v0 = reinterpret_cast<const f32x4*>(feats + (size_t)idx[rr    ] * FEAT)[lane];
            f32x4 v1 = reinterpret_cast<const f32x4*>(feats + (size_t)idx[rr + 1] * FEAT)[lane];
            f32x4 v2 = reinterpret_cast<const f32x4*>(feats + (size_t)idx[rr + 2] * FEAT)[lane];
            f32x4 v3 = reinterpret_cast<const f32x4*>(feats + (size_t)idx[rr + 3] * FEAT)[lane];
            f32x4 v4 = reinterpret_cast<const f32x4*>(feats + (size_t)idx[rr + 4] * FEAT)[lane];
            f32x4 v5 = reinterpret_cast<const f32x4*>(feats + (size_t)idx[rr + 5] * FEAT)[lane];
            f32x4 v6 = reinterpret_cast<const f32x4*>(feats + (size_t)idx[rr + 6] * FEAT)[lane];
            f32x4 v7 = reinterpret_cast<const f32x4*>(feats + (size_t)idx[rr + 7] * FEAT)[lane];
            acc += (v0 + v1) + (v2 + v3) + ((v4 + v5) + (v6 + v7));
        }
        for (; rr < e; ++rr) {
            acc += reinterpret_cast<const f32x4*>(feats + (size_t)idx[rr] * FEAT)[lane];
        }
        float* dst = accum + (size_t)cs * FEAT + lane * 4;
        atomicAdd(dst + 0, acc.x);
        atomicAdd(dst + 1, acc.y);
        atomicAdd(dst + 2, acc.z);
        atomicAdd(dst + 3, acc.w);
        r = e;
    }
}

// ---- phase E: normalize + mask + blend epilogue ----
__global__ void k_final(const float* __restrict__ accum, const float* __restrict__ mean,
                        const float* __restrict__ amount, const int* __restrict__ totals,
                        float* __restrict__ out) {
    const int seg  = blockIdx.x;
    const int lane = threadIdx.x;  // 64 threads
    const int cnt  = totals[seg];
    f32x4 s = reinterpret_cast<const f32x4*>(accum)[(size_t)seg * F4 + lane];
    float inv = 1.0f / ((float)cnt + EPS);
    f32x4 tm = s * inv;

    float lsum = tm.x + tm.y + tm.z + tm.w;
    for (int off = 1; off < 64; off <<= 1) lsum += __shfl_xor(lsum, off, 64);
    bool msk = (lsum != 0.0f);

    f32x4 m4 = reinterpret_cast<const f32x4*>(mean)[(size_t)seg * F4 + lane];
    f32x4 o = msk ? (m4 * BETA + tm * (1.0f - BETA)) : m4;
    reinterpret_cast<f32x4*>(out)[(size_t)seg * F4 + lane] = o;
    if (lane == 0) {
        out[(size_t)NSEG * FEAT + seg] = (cnt > 0) ? 1.0f : amount[seg];
    }
}

// ---------------- fallback (workspace too small): atomic accumulate into d_out ----------------
__global__ void k_fb_zero(float* __restrict__ out, int total) {
    int stride = gridDim.x * blockDim.x;
    for (int i = blockIdx.x * blockDim.x + threadIdx.x; i < total; i += stride) out[i] = 0.f;
}

__global__ void k_fb_acc(const float* __restrict__ feats, const int* __restrict__ labels,
                         const int* __restrict__ domains, int n, float* __restrict__ out) {
    int lane   = threadIdx.x & 63;
    int gwave  = (blockIdx.x * blockDim.x + threadIdx.x) >> 6;
    int nwaves = (gridDim.x * blockDim.x) >> 6;
    for (int i = gwave; i < n; i += nwaves) {
        int seg = domains[i] * NCLS + labels[i];
        const float4 v = reinterpret_cast<const float4*>(feats + (size_t)i * FEAT)[lane];
        float* dst = out + (size_t)seg * FEAT + lane * 4;
        atomicAdd(dst + 0, v.x);
        atomicAdd(dst + 1, v.y);
        atomicAdd(dst + 2, v.z);
        atomicAdd(dst + 3, v.w);
        if (lane == 0) atomicAdd(out + (size_t)NSEG * FEAT + seg, 1.0f);
    }
}

__global__ void k_fb_epi(const float* __restrict__ mean, const float* __restrict__ amount,
                         float* __restrict__ out) {
    int seg  = blockIdx.x;
    int lane = threadIdx.x;  // 64 threads
    float cntf = out[(size_t)NSEG * FEAT + seg];
    float4 s = reinterpret_cast<float4*>(out)[(size_t)seg * F4 + lane];
    float inv = 1.0f / (cntf + EPS);
    float4 tm = make_float4(s.x * inv, s.y * inv, s.z * inv, s.w * inv);
    float lsum = tm.x + tm.y + tm.z + tm.w;
    for (int off = 1; off < 64; off <<= 1) lsum += __shfl_xor(lsum, off, 64);
    bool msk = (lsum != 0.0f);
    float4 m4 = reinterpret_cast<const float4*>(mean)[(size_t)seg * F4 + lane];
    float4 o;
    if (msk) {
        o.x = m4.x * BETA + tm.x * (1.f - BETA);
        o.y = m4.y * BETA + tm.y * (1.f - BETA);
        o.z = m4.z * BETA + tm.z * (1.f - BETA);
        o.w = m4.w * BETA + tm.w * (1.f - BETA);
    } else {
        o = m4;
    }
    reinterpret_cast<float4*>(out)[(size_t)seg * F4 + lane] = o;
    if (lane == 0) {
        out[(size_t)NSEG * FEAT + seg] = (cntf > 0.5f) ? 1.0f : amount[seg];
    }
}

extern "C" void kernel_launch(void* const* d_in, const int* in_sizes, int n_in,
                              void* d_out, int out_size, void* d_ws, size_t ws_size,
                              hipStream_t stream) {
    const float* feats   = (const float*)d_in[0];
    const float* mean    = (const float*)d_in[1];
    const float* amount  = (const float*)d_in[2];
    const int*   labels  = (const int*)d_in[3];
    const int*   domains = (const int*)d_in[4];
    float* out = (float*)d_out;
    const int n = in_sizes[3];  // number of rows
    const int chunk = (n + SB - 1) / SB;

    // tiles for the heavy pass: prefer exactly 2048 uniform tiles (all co-resident)
    int grid_p = 2048;
    int tpt    = (n + grid_p - 1) / grid_p;
    if (tpt > MAXT) { tpt = MAXT; grid_p = (n + MAXT - 1) / MAXT; }

    // ws: seg[n] | W[SB*NSEG] | totals[NSEG] | offsets[NSEG] | Bmat[SB*NSEG]
    //     | sorted[n] | sseg[n] | accum[NSEG*FEAT floats]
    size_t need = ((size_t)n * 3 + (size_t)SB * NSEG * 2 + (size_t)NSEG * 2
                   + (size_t)NSEG * FEAT) * sizeof(int);
    if (ws_size >= need) {
        int* seg     = (int*)d_ws;
        int* W       = seg + n;
        int* totals  = W + (size_t)SB * NSEG;
        int* offsets = totals + NSEG;
        int* Bmat    = offsets + NSEG;
        int* sorted  = Bmat + (size_t)SB * NSEG;
        int* sseg    = sorted + n;
        float* accum = (float*)(sseg + n);

        k_zero_accum<<<(NSEG * F4 + 255) / 256, 256, 0, stream>>>(accum);
        k_seg_hist<<<SB, 256, 0, stream>>>(labels, domains, n, chunk, seg, W);
        k_totals<<<NSEG, 64, 0, stream>>>(W, totals);
        k_scan<<<1, 256, 0, stream>>>(totals, offsets);
        k_bases<<<NSEG, 256, 0, stream>>>(W, offsets, Bmat);
        k_scatter<<<SB, 256, 0, stream>>>(seg, n, chunk, Bmat, sorted, sseg);
        k_partial<<<grid_p, 256, 0, stream>>>(feats, sorted, sseg, n, tpt, accum);
        k_final<<<NSEG, 64, 0, stream>>>(accum, mean, amount, totals, out);
    } else {
        int total = NSEG * FEAT + NSEG;
        k_fb_zero<<<(total + 255) / 256, 256, 0, stream>>>(out, total);
        k_fb_acc<<<2048, 256, 0, stream>>>(feats, labels, domains, n, out);
        k_fb_epi<<<NSEG, 64, 0, stream>>>(mean, amount, out);
    }
}

// Round 5
// 237.325 us; speedup vs baseline: 1.1281x; 1.1281x over previous
//
#include <hip/hip_runtime.h>
#include <stddef.h>

constexpr int FEAT = 256;
constexpr int F4   = FEAT / 4;       // 64 float4 per row
constexpr int NCLS = 345;
constexpr int NDOM = 6;
constexpr int NSEG = NCLS * NDOM;    // 2070
constexpr int SB   = 256;            // scatter blocks (== k_bases block size)
constexpr float BETA = 0.5f;
constexpr float EPS  = 1e-5f;

typedef float f32x4 __attribute__((ext_vector_type(4)));

// ---- phase A: seg[] + per-block histogram (no global atomics) ----
__global__ void __launch_bounds__(256)
k_seg_hist(const int* __restrict__ labels, const int* __restrict__ domains,
           int n, int chunk, int* __restrict__ seg, int* __restrict__ W) {
    __shared__ int h[NSEG];
    for (int i = threadIdx.x; i < NSEG; i += blockDim.x) h[i] = 0;
    __syncthreads();
    const int b  = blockIdx.x;
    const int lo = b * chunk;
    const int hi = min(n, lo + chunk);
    for (int i = lo + threadIdx.x; i < hi; i += blockDim.x) {
        int s = domains[i] * NCLS + labels[i];
        seg[i] = s;
        atomicAdd(&h[s], 1);
    }
    __syncthreads();
    int* Wb = W + (size_t)b * NSEG;
    for (int i = threadIdx.x; i < NSEG; i += blockDim.x) Wb[i] = h[i];
}

// ---- phase B1 (fused): per-block LOCAL prefix -> Bmat, column total -> totals ----
__global__ void __launch_bounds__(256)
k_bases_tot(const int* __restrict__ W, int* __restrict__ Bmat,
            int* __restrict__ totals) {
    const int s = blockIdx.x;
    const int t = threadIdx.x;  // 256 == SB
    __shared__ int sc[SB];
    int w = W[(size_t)t * NSEG + s];
    sc[t] = w;
    __syncthreads();
    for (int off = 1; off < SB; off <<= 1) {
        int v = (t >= off) ? sc[t - off] : 0;
        __syncthreads();
        sc[t] += v;
        __syncthreads();
    }
    Bmat[(size_t)t * NSEG + s] = sc[t] - w;   // local exclusive prefix
    if (t == SB - 1) totals[s] = sc[t];
}

// ---- phase B2: exclusive scan of totals -> offsets (single block) ----
__global__ void k_scan(const int* __restrict__ totals, int* __restrict__ offsets) {
    constexpr int T  = 256;
    constexpr int CH = (NSEG + T - 1) / T;  // 9
    __shared__ int csum[T];
    int t = threadIdx.x;
    int base = t * CH;
    int sum = 0;
    for (int j = 0; j < CH; ++j) {
        int idx = base + j;
        if (idx < NSEG) sum += totals[idx];
    }
    csum[t] = sum;
    __syncthreads();
    for (int off = 1; off < T; off <<= 1) {
        int v = (t >= off) ? csum[t - off] : 0;
        __syncthreads();
        csum[t] += v;
        __syncthreads();
    }
    int run = csum[t] - sum;
    for (int j = 0; j < CH; ++j) {
        int idx = base + j;
        if (idx < NSEG) {
            offsets[idx] = run;
            run += totals[idx];
        }
    }
}

// ---- phase C: scatter row indices (LDS cursors = local base + global offset) ----
__global__ void __launch_bounds__(256)
k_scatter(const int* __restrict__ seg, int n, int chunk,
          const int* __restrict__ Bmat, const int* __restrict__ offsets,
          int* __restrict__ sorted) {
    __shared__ int cur[NSEG];
    const int b = blockIdx.x;
    const int* Bb = Bmat + (size_t)b * NSEG;
    for (int i = threadIdx.x; i < NSEG; i += blockDim.x) cur[i] = Bb[i] + offsets[i];
    __syncthreads();
    const int lo = b * chunk;
    const int hi = min(n, lo + chunk);
    for (int i = lo + threadIdx.x; i < hi; i += blockDim.x) {
        int s = seg[i];
        int pos = atomicAdd(&cur[s], 1);
        sorted[pos] = i;
    }
}

// ---- phase D: per-segment reduce + fused epilogue (one block per segment) ----
__global__ void __launch_bounds__(256)
k_reduce(const float* __restrict__ feats, const float* __restrict__ mean,
         const float* __restrict__ amount, const int* __restrict__ sorted,
         const int* __restrict__ counts, const int* __restrict__ offsets,
         float* __restrict__ out) {
    const int seg  = blockIdx.x;
    const int cnt  = counts[seg];
    const int base = offsets[seg];
    const int lane = threadIdx.x & 63;   // which float4 of the row
    const int rp   = threadIdx.x >> 6;   // row-parallel wave 0..3

    f32x4 acc = (f32x4)0.0f;
    int r = rp;
    // 8 rows in flight per wave (8 KB) to hide gather latency
    for (; r + 28 < cnt; r += 32) {
        int i0 = sorted[base + r];
        int i1 = sorted[base + r + 4];
        int i2 = sorted[base + r + 8];
        int i3 = sorted[base + r + 12];
        int i4 = sorted[base + r + 16];
        int i5 = sorted[base + r + 20];
        int i6 = sorted[base + r + 24];
        int i7 = sorted[base + r + 28];
        f32x4 v0 = reinterpret_cast<const f32x4*>(feats + (size_t)i0 * FEAT)[lane];
        f32x4 v1 = reinterpret_cast<const f32x4*>(feats + (size_t)i1 * FEAT)[lane];
        f32x4 v2 = reinterpret_cast<const f32x4*>(feats + (size_t)i2 * FEAT)[lane];
        f32x4 v3 = reinterpret_cast<const f32x4*>(feats + (size_t)i3 * FEAT)[lane];
        f32x4 v4 = reinterpret_cast<const f32x4*>(feats + (size_t)i4 * FEAT)[lane];
        f32x4 v5 = reinterpret_cast<const f32x4*>(feats + (size_t)i5 * FEAT)[lane];
        f32x4 v6 = reinterpret_cast<const f32x4*>(feats + (size_t)i6 * FEAT)[lane];
        f32x4 v7 = reinterpret_cast<const f32x4*>(feats + (size_t)i7 * FEAT)[lane];
        acc += (v0 + v1) + (v2 + v3) + ((v4 + v5) + (v6 + v7));
    }
    for (; r < cnt; r += 4) {
        int i0 = sorted[base + r];
        acc += reinterpret_cast<const f32x4*>(feats + (size_t)i0 * FEAT)[lane];
    }

    __shared__ f32x4 sh[4][F4];
    sh[rp][lane] = acc;
    __syncthreads();
    if (rp == 0) {
        f32x4 s = acc + sh[1][lane] + sh[2][lane] + sh[3][lane];
        float inv = 1.0f / ((float)cnt + EPS);
        f32x4 tm = s * inv;

        float lsum = tm.x + tm.y + tm.z + tm.w;
        for (int off = 1; off < 64; off <<= 1) lsum += __shfl_xor(lsum, off, 64);
        bool msk = (lsum != 0.0f);

        f32x4 m4 = reinterpret_cast<const f32x4*>(mean)[(size_t)seg * F4 + lane];
        f32x4 o = msk ? (m4 * BETA + tm * (1.0f - BETA)) : m4;
        reinterpret_cast<f32x4*>(out)[(size_t)seg * F4 + lane] = o;
        if (lane == 0) {
            out[(size_t)NSEG * FEAT + seg] = (cnt > 0) ? 1.0f : amount[seg];
        }
    }
}

// ---------------- fallback (workspace too small): atomic accumulate into d_out ----------------
__global__ void k_fb_zero(float* __restrict__ out, int total) {
    int stride = gridDim.x * blockDim.x;
    for (int i = blockIdx.x * blockDim.x + threadIdx.x; i < total; i += stride) out[i] = 0.f;
}

__global__ void k_fb_acc(const float* __restrict__ feats, const int* __restrict__ labels,
                         const int* __restrict__ domains, int n, float* __restrict__ out) {
    int lane   = threadIdx.x & 63;
    int gwave  = (blockIdx.x * blockDim.x + threadIdx.x) >> 6;
    int nwaves = (gridDim.x * blockDim.x) >> 6;
    for (int i = gwave; i < n; i += nwaves) {
        int seg = domains[i] * NCLS + labels[i];
        const float4 v = reinterpret_cast<const float4*>(feats + (size_t)i * FEAT)[lane];
        float* dst = out + (size_t)seg * FEAT + lane * 4;
        atomicAdd(dst + 0, v.x);
        atomicAdd(dst + 1, v.y);
        atomicAdd(dst + 2, v.z);
        atomicAdd(dst + 3, v.w);
        if (lane == 0) atomicAdd(out + (size_t)NSEG * FEAT + seg, 1.0f);
    }
}

__global__ void k_fb_epi(const float* __restrict__ mean, const float* __restrict__ amount,
                         float* __restrict__ out) {
    int seg  = blockIdx.x;
    int lane = threadIdx.x;  // 64 threads
    float cntf = out[(size_t)NSEG * FEAT + seg];
    float4 s = reinterpret_cast<float4*>(out)[(size_t)seg * F4 + lane];
    float inv = 1.0f / (cntf + EPS);
    float4 tm = make_float4(s.x * inv, s.y * inv, s.z * inv, s.w * inv);
    float lsum = tm.x + tm.y + tm.z + tm.w;
    for (int off = 1; off < 64; off <<= 1) lsum += __shfl_xor(lsum, off, 64);
    bool msk = (lsum != 0.0f);
    float4 m4 = reinterpret_cast<const float4*>(mean)[(size_t)seg * F4 + lane];
    float4 o;
    if (msk) {
        o.x = m4.x * BETA + tm.x * (1.f - BETA);
        o.y = m4.y * BETA + tm.y * (1.f - BETA);
        o.z = m4.z * BETA + tm.z * (1.f - BETA);
        o.w = m4.w * BETA + tm.w * (1.f - BETA);
    } else {
        o = m4;
    }
    reinterpret_cast<float4*>(out)[(size_t)seg * F4 + lane] = o;
    if (lane == 0) {
        out[(size_t)NSEG * FEAT + seg] = (cntf > 0.5f) ? 1.0f : amount[seg];
    }
}

extern "C" void kernel_launch(void* const* d_in, const int* in_sizes, int n_in,
                              void* d_out, int out_size, void* d_ws, size_t ws_size,
                              hipStream_t stream) {
    const float* feats   = (const float*)d_in[0];
    const float* mean    = (const float*)d_in[1];
    const float* amount  = (const float*)d_in[2];
    const int*   labels  = (const int*)d_in[3];
    const int*   domains = (const int*)d_in[4];
    float* out = (float*)d_out;
    const int n = in_sizes[3];  // number of rows
    const int chunk = (n + SB - 1) / SB;

    // ws layout: seg[n] | W[SB*NSEG] | totals[NSEG] | offsets[NSEG] | Bmat[SB*NSEG] | sorted[n]
    size_t need = ((size_t)n * 2 + (size_t)SB * NSEG * 2 + (size_t)NSEG * 2) * sizeof(int);
    if (ws_size >= need) {
        int* seg     = (int*)d_ws;
        int* W       = seg + n;
        int* totals  = W + (size_t)SB * NSEG;
        int* offsets = totals + NSEG;
        int* Bmat    = offsets + NSEG;
        int* sorted  = Bmat + (size_t)SB * NSEG;

        k_seg_hist<<<SB, 256, 0, stream>>>(labels, domains, n, chunk, seg, W);
        k_bases_tot<<<NSEG, 256, 0, stream>>>(W, Bmat, totals);
        k_scan<<<1, 256, 0, stream>>>(totals, offsets);
        k_scatter<<<SB, 256, 0, stream>>>(seg, n, chunk, Bmat, offsets, sorted);
        k_reduce<<<NSEG, 256, 0, stream>>>(feats, mean, amount, sorted, totals, offsets, out);
    } else {
        int total = NSEG * FEAT + NSEG;
        k_fb_zero<<<(total + 255) / 256, 256, 0, stream>>>(out, total);
        k_fb_acc<<<2048, 256, 0, stream>>>(feats, labels, domains, n, out);
        k_fb_epi<<<NSEG, 64, 0, stream>>>(mean, amount, out);
    }
}